// Round 12
// baseline (199.873 us; speedup 1.0000x reference)
//
#include <hip/hip_runtime.h>
#include <hip/hip_fp16.h>
#include <math.h>

#define N_NODES 100000
#define F_IN    100
#define HIDDEN  16
#define N_CLASS 18

#define BKT_SHIFT 7
#define BKT_NODES 128                                   // nodes per bucket
#define NBKT ((N_NODES + BKT_NODES - 1) / BKT_NODES)    // 782
#define TILE_B 4096                                     // edges per split tile
#define SORT_CAP 5120                                   // max edges per bucket

// ---- inline edge dtype detection: int64 little-endian (values < 2^31) has all-zero odd words
__device__ __forceinline__ int detect64(const int* __restrict__ ei) {
    int z = 1;
#pragma unroll
    for (int i = 0; i < 16; ++i)
        if (ei[2 * i + 1] != 0) z = 0;
    return z;
}

__device__ __forceinline__ int edge_at(const int* __restrict__ ei, long long idx, int is64) {
    return is64 ? ei[2 * idx] : ei[idx];
}

// ---- per-tile bucket histograms (2 tiles of 4096 per block) + global bucket counts
__global__ __launch_bounds__(512) void k_bcnt(const int* __restrict__ ei, long long E,
                                              int nt,
                                              int* __restrict__ bcnt,
                                              int* __restrict__ thist) {
    __shared__ int hist0[NBKT];
    __shared__ int hist1[NBKT];
    int tid = threadIdx.x;
    for (int i = tid; i < NBKT; i += 512) { hist0[i] = 0; hist1[i] = 0; }
    __syncthreads();
    int is64 = detect64(ei);
    long long base = (long long)blockIdx.x * (2 * TILE_B);
    long long rem = E - base;
    int ntot = (int)((rem < (long long)(2 * TILE_B)) ? rem : (long long)(2 * TILE_B));
    int n0 = ntot < TILE_B ? ntot : TILE_B;
    int n1 = ntot - n0;
    for (int i = tid; i < n0; i += 512) {
        int d = edge_at(ei, E + base + i, is64);
        atomicAdd(&hist0[d >> BKT_SHIFT], 1);
    }
    for (int i = tid; i < n1; i += 512) {
        int d = edge_at(ei, E + base + TILE_B + i, is64);
        atomicAdd(&hist1[d >> BKT_SHIFT], 1);
    }
    __syncthreads();
    int t0 = blockIdx.x * 2, t1 = t0 + 1;
    for (int b = tid; b < NBKT; b += 512) {
        int c0 = hist0[b], c1 = hist1[b];
        thist[t0 * NBKT + b] = c0;
        if (n1 > 0) thist[t1 * NBKT + b] = c1;
        int c = c0 + c1;
        if (c) atomicAdd(&bcnt[b], c);
    }
}

// ---- single-block scan over 782 bucket counts -> bucket bases
__global__ __launch_bounds__(1024) void k_bktscan(const int* __restrict__ bcnt,
                                                  int* __restrict__ bkt_base) {
    __shared__ int s[1024];
    int tid = threadIdx.x;
    int v = (tid < NBKT) ? bcnt[tid] : 0;
    s[tid] = v;
    __syncthreads();
    for (int off = 1; off < 1024; off <<= 1) {
        int t = (tid >= off) ? s[tid - off] : 0;
        __syncthreads();
        s[tid] += t;
        __syncthreads();
    }
    if (tid < NBKT) bkt_base[tid] = s[tid] - v;   // exclusive
    if (tid == 1023) bkt_base[NBKT] = s[1023];
}

// ---- per-bucket prefix over tiles: tbase[t][b] = bkt_base[b] + sum_{t'<t} thist[t'][b]
__global__ __launch_bounds__(256) void k_tscan(const int* __restrict__ thist,
                                               const int* __restrict__ bkt_base,
                                               int nt,
                                               int* __restrict__ tbase) {
    __shared__ int ts[256];
    int b = blockIdx.x, tid = threadIdx.x;
    int t0 = tid * 4;
    int c[4];
#pragma unroll
    for (int j = 0; j < 4; ++j) {
        int t = t0 + j;
        c[j] = (t < nt) ? thist[t * NBKT + b] : 0;
    }
    int s = c[0] + c[1] + c[2] + c[3];
    ts[tid] = s;
    __syncthreads();
    for (int off = 1; off < 256; off <<= 1) {
        int t = (tid >= off) ? ts[tid - off] : 0;
        __syncthreads();
        ts[tid] += t;
        __syncthreads();
    }
    int run = bkt_base[b] + ts[tid] - s;
#pragma unroll
    for (int j = 0; j < 4; ++j) {
        int t = t0 + j;
        if (t < nt) { tbase[t * NBKT + b] = run; run += c[j]; }
    }
}

// ---- split: per-tile counting sort by bucket, deterministic positions (no atomics)
// pairs[pos] = src | (dst&127)<<17
__global__ __launch_bounds__(512) void k_bucket(const int* __restrict__ ei, long long E,
                                                const int* __restrict__ thist,
                                                const int* __restrict__ tbase,
                                                int* __restrict__ pairs) {
    __shared__ int lbase[NBKT];
    __shared__ int gbase[NBKT];
    __shared__ int lcur[NBKT];
    __shared__ unsigned short perm[TILE_B];
    __shared__ int ts[512];
    int tid = threadIdx.x;
    int t = blockIdx.x;
    int is64 = detect64(ei);
    long long e0 = (long long)t * TILE_B;
    int n = (int)(((E - e0) < (long long)TILE_B) ? (E - e0) : (long long)TILE_B);

    // load tile hist + tile base (coalesced), scan hist -> lbase (2 buckets/thread)
    int b0 = tid * 2;
    int h0 = (b0 + 0 < NBKT) ? thist[t * NBKT + b0 + 0] : 0;
    int h1 = (b0 + 1 < NBKT) ? thist[t * NBKT + b0 + 1] : 0;
    int tsum = h0 + h1;
    ts[tid] = tsum;
    for (int b = tid; b < NBKT; b += 512) gbase[b] = tbase[t * NBKT + b];
    __syncthreads();
    for (int off = 1; off < 512; off <<= 1) {
        int tv = (tid >= off) ? ts[tid - off] : 0;
        __syncthreads();
        ts[tid] += tv;
        __syncthreads();
    }
    int eb = ts[tid] - tsum;
    if (b0 + 0 < NBKT) { lbase[b0 + 0] = eb;      lcur[b0 + 0] = eb; }
    if (b0 + 1 < NBKT) { lbase[b0 + 1] = eb + h0; lcur[b0 + 1] = eb + h0; }
    __syncthreads();

    // local binning (perm holds tile-local edge ids, grouped by bucket)
    for (int i = tid; i < n; i += 512) {
        int d = edge_at(ei, E + e0 + i, is64);
        int l = atomicAdd(&lcur[d >> BKT_SHIFT], 1);
        perm[l] = (unsigned short)i;
    }
    __syncthreads();

    // write out: consecutive k within a bucket-run -> consecutive positions
    for (int k = tid; k < n; k += 512) {
        int i = perm[k];
        int s = edge_at(ei, e0 + i, is64);
        int d = edge_at(ei, E + e0 + i, is64);
        int b = d >> BKT_SHIFT;
        int pos = gbase[b] + (k - lbase[b]);
        pairs[pos] = s | ((d & (BKT_NODES - 1)) << 17);
    }
}

// ---- fused CSR finalize: per bucket -> per-node counts, dinv, row_start, in-place sort
__global__ __launch_bounds__(256) void k_csr(const int* __restrict__ bkt_base,
                                             int* __restrict__ pairs,
                                             int* __restrict__ row_start,
                                             float* __restrict__ dinv) {
    __shared__ int stage[SORT_CAP];
    __shared__ int lc[BKT_NODES];
    __shared__ int rs[BKT_NODES];
    int bk = blockIdx.x, tid = threadIdx.x;
    int i0 = bkt_base[bk], i1 = bkt_base[bk + 1];
    int m = i1 - i0;
    if (tid < BKT_NODES) lc[tid] = 0;
    __syncthreads();
    for (int i = tid; i < m; i += 256) {
        int v = pairs[i0 + i];
        stage[i] = v;
        atomicAdd(&lc[v >> 17], 1);
    }
    __syncthreads();
    if (tid < BKT_NODES) rs[tid] = lc[tid];
    __syncthreads();
    for (int off = 1; off < BKT_NODES; off <<= 1) {
        int t = (tid >= off && tid < BKT_NODES) ? rs[tid - off] : 0;
        __syncthreads();
        if (tid < BKT_NODES) rs[tid] += t;
        __syncthreads();
    }
    int node = bk * BKT_NODES + tid;
    int ex = 0;
    if (tid < BKT_NODES) {
        int c = lc[tid];
        ex = rs[tid] - c;          // exclusive local prefix
        if (node < N_NODES) {
            row_start[node] = i0 + ex;
            dinv[node] = rsqrtf((float)c + 1.0f);
        }
    }
    if (bk == NBKT - 1 && tid == 0) row_start[N_NODES] = i1;
    __syncthreads();
    if (tid < BKT_NODES) lc[tid] = ex;   // reuse as cursor
    __syncthreads();
    for (int i = tid; i < m; i += 256) {
        int v = stage[i];
        int pos = atomicAdd(&lc[v >> 17], 1);
        pairs[i0 + pos] = v & 0x1FFFF;
    }
}

// ---- fused split-K: tmpp = fp16( dinv * ( relu(x@W1+b1) @ Wc0 ) ); 2 threads/node
__global__ __launch_bounds__(512) void k_lin1f(const float* __restrict__ x,
                                               const float* __restrict__ W1,
                                               const float* __restrict__ b1,
                                               const float* __restrict__ Wc0,
                                               const float* __restrict__ dinv,
                                               __half* __restrict__ tmpp) {
    __shared__ float sW[F_IN * HIDDEN];
    __shared__ float sb[HIDDEN];
    __shared__ float sW2[HIDDEN * HIDDEN];
    for (int i = threadIdx.x; i < F_IN * HIDDEN; i += 512) sW[i] = W1[i];
    if (threadIdx.x < HIDDEN) sb[threadIdx.x] = b1[threadIdx.x];
    if (threadIdx.x >= 32 && threadIdx.x < 32 + HIDDEN * HIDDEN)
        sW2[threadIdx.x - 32] = Wc0[threadIdx.x - 32];
    __syncthreads();
    int node = blockIdx.x * 256 + (threadIdx.x >> 1);
    int half = threadIdx.x & 1;
    if (node >= N_NODES) return;

    float acc[HIDDEN];
#pragma unroll
    for (int j = 0; j < HIDDEN; ++j) acc[j] = half ? 0.0f : sb[j];

    const float4* x4 = reinterpret_cast<const float4*>(x + (long long)node * F_IN);
    int k40 = half ? 13 : 0;
    int k41 = half ? 25 : 13;
    for (int k4 = k40; k4 < k41; ++k4) {
        float4 xv = x4[k4];
        const float* w = &sW[k4 * 4 * HIDDEN];
#pragma unroll
        for (int j = 0; j < HIDDEN; ++j) {
            acc[j] += xv.x * w[0 * HIDDEN + j];
            acc[j] += xv.y * w[1 * HIDDEN + j];
            acc[j] += xv.z * w[2 * HIDDEN + j];
            acc[j] += xv.w * w[3 * HIDDEN + j];
        }
    }
    // combine halves (both lanes end with the full sum), relu
#pragma unroll
    for (int j = 0; j < HIDDEN; ++j) {
        acc[j] += __shfl_xor(acc[j], 1);
        acc[j] = fmaxf(acc[j], 0.0f);
    }
    // each half computes its 8 outputs of the 16x16 transform
    float out[8];
#pragma unroll
    for (int j = 0; j < 8; ++j) out[j] = 0.0f;
    int j0 = half * 8;
#pragma unroll
    for (int k = 0; k < HIDDEN; ++k) {
        float hk = acc[k];
#pragma unroll
        for (int j = 0; j < 8; ++j) out[j] += hk * sW2[k * HIDDEN + j0 + j];
    }
    float di = dinv[node];
    __half2 packed[4];
#pragma unroll
    for (int j = 0; j < 4; ++j)
        packed[j] = __floats2half2_rn(di * out[2 * j], di * out[2 * j + 1]);
    *reinterpret_cast<float4*>(tmpp + (long long)node * HIDDEN + half * 8) =
        *reinterpret_cast<const float4*>(packed);
}

// ---- tmp' = fp16( dinv[i] * (h @ W) )
__global__ __launch_bounds__(256) void k_mm16(const float* __restrict__ h,
                                              const float* __restrict__ W,
                                              const float* __restrict__ dinv,
                                              __half* __restrict__ tmpp) {
    __shared__ float sW[HIDDEN * HIDDEN];
    if (threadIdx.x < HIDDEN * HIDDEN) sW[threadIdx.x] = W[threadIdx.x];
    __syncthreads();
    int node = blockIdx.x * 256 + threadIdx.x;
    if (node >= N_NODES) return;

    float hv[HIDDEN];
    const float4* hr = reinterpret_cast<const float4*>(h + (long long)node * HIDDEN);
#pragma unroll
    for (int q = 0; q < HIDDEN / 4; ++q) {
        float4 v = hr[q];
        hv[q * 4 + 0] = v.x; hv[q * 4 + 1] = v.y;
        hv[q * 4 + 2] = v.z; hv[q * 4 + 3] = v.w;
    }
    float di = dinv[node];
    float out[HIDDEN];
#pragma unroll
    for (int j = 0; j < HIDDEN; ++j) out[j] = 0.0f;
#pragma unroll
    for (int k = 0; k < HIDDEN; ++k) {
        float hk = hv[k];
#pragma unroll
        for (int j = 0; j < HIDDEN; ++j) out[j] += hk * sW[k * HIDDEN + j];
    }
    __half2 packed[8];
#pragma unroll
    for (int j = 0; j < 8; ++j)
        packed[j] = __floats2half2_rn(di * out[2 * j], di * out[2 * j + 1]);
    float4* tp = reinterpret_cast<float4*>(tmpp + (long long)node * HIDDEN);
    const float4* ps = reinterpret_cast<const float4*>(packed);
    tp[0] = ps[0];
    tp[1] = ps[1];
}

// ---- wave-per-node register pull, 4 lanes/row; fused epilogue
__global__ __launch_bounds__(256) void k_aggr(const int* __restrict__ row_start,
                                              const int* __restrict__ srcs,
                                              const __half* __restrict__ tmpp,
                                              const float* __restrict__ dinv,
                                              const float* __restrict__ b,
                                              float* __restrict__ h) {
    int wave = (blockIdx.x * 256 + threadIdx.x) >> 6;   // node id
    if (wave >= N_NODES) return;
    int lane = threadIdx.x & 63;
    int es = lane >> 2;        // edge slot 0..15
    int fq = lane & 3;         // feature quarter (4 halves = 8 B)

    int s0 = row_start[wave], s1 = row_start[wave + 1];
    float a0 = 0.0f, a1 = 0.0f, a2 = 0.0f, a3 = 0.0f;

    for (int e = s0 + es; e < s1; e += 16) {
        int src = srcs[e];
        float2 rv = *(reinterpret_cast<const float2*>(
                          tmpp + (long long)src * HIDDEN) + fq);
        const __half2* h2 = reinterpret_cast<const __half2*>(&rv);
        float2 f0 = __half22float2(h2[0]);
        float2 f1 = __half22float2(h2[1]);
        a0 += f0.x; a1 += f0.y; a2 += f1.x; a3 += f1.y;
    }
#pragma unroll
    for (int m = 4; m <= 32; m <<= 1) {
        a0 += __shfl_xor(a0, m);
        a1 += __shfl_xor(a1, m);
        a2 += __shfl_xor(a2, m);
        a3 += __shfl_xor(a3, m);
    }
    if (es == 0) {
        float2 sv = *(reinterpret_cast<const float2*>(
                          tmpp + (long long)wave * HIDDEN) + fq);
        const __half2* s2 = reinterpret_cast<const __half2*>(&sv);
        float2 f0 = __half22float2(s2[0]);
        float2 f1 = __half22float2(s2[1]);
        float di = dinv[wave];
        float4 bv = *(reinterpret_cast<const float4*>(b) + fq);
        float4 o;
        o.x = fmaxf(di * (a0 + f0.x) + bv.x, 0.0f);
        o.y = fmaxf(di * (a1 + f0.y) + bv.y, 0.0f);
        o.z = fmaxf(di * (a2 + f1.x) + bv.z, 0.0f);
        o.w = fmaxf(di * (a3 + f1.y) + bv.w, 0.0f);
        *(reinterpret_cast<float4*>(h + (long long)wave * HIDDEN) + fq) = o;
    }
}

// ---- out = log_softmax(h @ W2 + b2)
__global__ __launch_bounds__(256) void k_out(const float* __restrict__ h,
                                             const float* __restrict__ W2,
                                             const float* __restrict__ b2,
                                             float* __restrict__ out) {
    __shared__ float sW[HIDDEN * N_CLASS];
    __shared__ float sb[N_CLASS];
    for (int i = threadIdx.x; i < HIDDEN * N_CLASS; i += 256) sW[i] = W2[i];
    if (threadIdx.x < N_CLASS) sb[threadIdx.x] = b2[threadIdx.x];
    __syncthreads();
    int node = blockIdx.x * 256 + threadIdx.x;
    if (node >= N_NODES) return;

    float hv[HIDDEN];
    const float4* hr = reinterpret_cast<const float4*>(h + (long long)node * HIDDEN);
#pragma unroll
    for (int q = 0; q < HIDDEN / 4; ++q) {
        float4 v = hr[q];
        hv[q * 4 + 0] = v.x; hv[q * 4 + 1] = v.y;
        hv[q * 4 + 2] = v.z; hv[q * 4 + 3] = v.w;
    }
    float z[N_CLASS];
#pragma unroll
    for (int c = 0; c < N_CLASS; ++c) z[c] = sb[c];
#pragma unroll
    for (int k = 0; k < HIDDEN; ++k) {
        float hk = hv[k];
#pragma unroll
        for (int c = 0; c < N_CLASS; ++c) z[c] += hk * sW[k * N_CLASS + c];
    }
    float m = z[0];
#pragma unroll
    for (int c = 1; c < N_CLASS; ++c) m = fmaxf(m, z[c]);
    float ssum = 0.0f;
#pragma unroll
    for (int c = 0; c < N_CLASS; ++c) ssum += expf(z[c] - m);
    float l = m + logf(ssum);
    float* orow = out + (long long)node * N_CLASS;
#pragma unroll
    for (int c = 0; c < N_CLASS; ++c) orow[c] = z[c] - l;
}

static inline char* align256(char* p) {
    return (char*)(((size_t)p + 255) & ~(size_t)255);
}

extern "C" void kernel_launch(void* const* d_in, const int* in_sizes, int n_in,
                              void* d_out, int out_size, void* d_ws, size_t ws_size,
                              hipStream_t stream) {
    const float* x   = (const float*)d_in[0];
    const int*   ei  = (const int*)d_in[1];
    const float* W1  = (const float*)d_in[2];
    const float* b1  = (const float*)d_in[3];
    const float* Wc0 = (const float*)d_in[4];
    const float* bc0 = (const float*)d_in[5];
    const float* Wc1 = (const float*)d_in[6];
    const float* bc1 = (const float*)d_in[7];
    const float* W2  = (const float*)d_in[8];
    const float* b2  = (const float*)d_in[9];
    float* out = (float*)d_out;

    long long E = (long long)in_sizes[1] / 2;
    int nt = (int)((E + TILE_B - 1) / TILE_B);          // number of split tiles

    char* p = (char*)d_ws;
    float* dinv    = (float*)p;          p = align256(p + sizeof(float) * N_NODES);
    int* row_start = (int*)p;            p = align256(p + sizeof(int) * (N_NODES + 1));
    int* bcnt      = (int*)p;            p = align256(p + sizeof(int) * NBKT);
    int* bkt_base  = (int*)p;            p = align256(p + sizeof(int) * (NBKT + 1));
    int* thist     = (int*)p;            p = align256(p + sizeof(int) * (size_t)nt * NBKT);
    int* tbase     = (int*)p;            p = align256(p + sizeof(int) * (size_t)nt * NBKT);
    int* pairs     = (int*)p;            p = align256(p + sizeof(int) * E);
    float* h       = (float*)p;          p = align256(p + sizeof(float) * (size_t)N_NODES * HIDDEN);
    __half* tmpp   = (__half*)p;         p = align256(p + sizeof(__half) * (size_t)N_NODES * HIDDEN);

    const int nblk_node = (N_NODES + 255) / 256;
    const int nblk_bcnt = (int)((E + 2 * TILE_B - 1) / (2 * TILE_B));
    const int nblk_aggr = (int)(((long long)N_NODES * 64 + 255) / 256);

    hipMemsetAsync(bcnt, 0, sizeof(int) * NBKT, stream);

    k_bcnt<<<nblk_bcnt, 512, 0, stream>>>(ei, E, nt, bcnt, thist);
    k_bktscan<<<1, 1024, 0, stream>>>(bcnt, bkt_base);
    k_tscan<<<NBKT, 256, 0, stream>>>(thist, bkt_base, nt, tbase);
    k_bucket<<<nt, 512, 0, stream>>>(ei, E, thist, tbase, pairs);
    k_csr<<<NBKT, 256, 0, stream>>>(bkt_base, pairs, row_start, dinv);

    // conv 1 (lin1 fused into the dense transform)
    k_lin1f<<<nblk_node, 512, 0, stream>>>(x, W1, b1, Wc0, dinv, tmpp);
    k_aggr<<<nblk_aggr, 256, 0, stream>>>(row_start, pairs, tmpp, dinv, bc0, h);

    // conv 2
    k_mm16<<<nblk_node, 256, 0, stream>>>(h, Wc1, dinv, tmpp);
    k_aggr<<<nblk_aggr, 256, 0, stream>>>(row_start, pairs, tmpp, dinv, bc1, h);

    k_out<<<nblk_node, 256, 0, stream>>>(h, W2, b2, out);
}